// Round 7
// baseline (259.810 us; speedup 1.0000x reference)
//
#include <hip/hip_runtime.h>
#include <math.h>

#define B_SZ 1024
#define E_SZ 512
#define C_SZ 16384
#define MRG 0.1f
#define ALPHA 32.0f
#define K_HY 1.0f
#define LAM 0.1f

#define NBLK 2048           // gemm grid: 128 col-blocks x 16 row-blocks
#define NFIN 64             // finalize participant blocks

typedef __bf16 bf16;
typedef bf16 bf16x8 __attribute__((ext_vector_type(8)));
typedef float f32x4 __attribute__((ext_vector_type(4)));

__device__ __forceinline__ void async16(const void* g, void* l) {
    __builtin_amdgcn_global_load_lds(
        (const __attribute__((address_space(1))) void*)g,
        (__attribute__((address_space(3))) void*)l,
        16, 0, 0);
}

// ---------------- prologue: one dispatch, 4352 blocks ----------------------
// blocks [0,4096):    proxy row-l2norm -> bf16 (4 rows/block, wave per row)
// blocks [4096,4352): coalesced input convert (8 floats/thread);
//                     threads t<16384 also: class scalars + zero accumulators
__global__ __launch_bounds__(256) void prologue(
    const float* __restrict__ proxies, bf16* __restrict__ Pbf,
    const float* __restrict__ effNum, const float* __restrict__ lSim,
    const float* __restrict__ x, bf16* __restrict__ Abf,
    float* __restrict__ oSim, float* __restrict__ iEff,
    float* __restrict__ posExp, float* __restrict__ negExp,
    float* __restrict__ negVals, int* __restrict__ posCnt,
    float* __restrict__ acc4, int* __restrict__ ctrl) {
    if (blockIdx.x < 4096) {
        int row = (blockIdx.x * 256 + threadIdx.x) >> 6;
        int lane = threadIdx.x & 63;
        const float* pr = proxies + (size_t)row * E_SZ + lane * 8;
        float4 v0 = *(const float4*)pr;
        float4 v1 = *(const float4*)(pr + 4);
        float ss = v0.x * v0.x + v0.y * v0.y + v0.z * v0.z + v0.w * v0.w +
                   v1.x * v1.x + v1.y * v1.y + v1.z * v1.z + v1.w * v1.w;
#pragma unroll
        for (int m = 1; m < 64; m <<= 1) ss += __shfl_xor(ss, m);
        float inv = 1.0f / sqrtf(ss + 1e-12f);
        bf16x8 o;
        o[0] = (bf16)(v0.x * inv); o[1] = (bf16)(v0.y * inv);
        o[2] = (bf16)(v0.z * inv); o[3] = (bf16)(v0.w * inv);
        o[4] = (bf16)(v1.x * inv); o[5] = (bf16)(v1.y * inv);
        o[6] = (bf16)(v1.z * inv); o[7] = (bf16)(v1.w * inv);
        *(bf16x8*)(Pbf + (size_t)row * E_SZ + lane * 8) = o;
    } else {
        int t = (blockIdx.x - 4096) * 256 + threadIdx.x;   // 0..65535
        size_t f0 = (size_t)t * 8;
        float4 v0 = *(const float4*)(x + f0);
        float4 v1 = *(const float4*)(x + f0 + 4);
        bf16x8 o;
        o[0] = (bf16)v0.x; o[1] = (bf16)v0.y; o[2] = (bf16)v0.z; o[3] = (bf16)v0.w;
        o[4] = (bf16)v1.x; o[5] = (bf16)v1.y; o[6] = (bf16)v1.z; o[7] = (bf16)v1.w;
        *(bf16x8*)(Abf + f0) = o;
        if (t < C_SZ) {
            float en = effNum[t], ls = lSim[t];
            float wb = 1.0f / (1.0f + log1pf(en));
            float eta = (1.0f + K_HY * (1.0f - ls)) * wb + LAM;
            oSim[t] = ls - eta;
            iEff[t] = 1.0f / fmaxf(1.0f, en);
            posExp[t] = 0.f; negExp[t] = 0.f; negVals[t] = 0.f; posCnt[t] = 0;
            if (t < 8) acc4[t] = 0.f;
            if (t < 3) ctrl[t] = 0;   // ticket, flag, ticket2
        }
    }
}

// -------- fused GEMM (bf16 MFMA) + epilogue + ticket-based finalize --------
// Tile: BM=64, BN=128, BK=32; grid (128,16) = 2048 blocks; 24.9 KB LDS ->
// 6 blocks/CU, 24 waves/CU resident. Unified LDS: A chunks 0-3, B chunks 4-11,
// chunk = 16 rows x 32 K in [kq][row] order (2-way-only bank aliasing, free).
// Each wave stages chunks [3w,3w+3). Last 64 tickets run the finalize.
__global__ __launch_bounds__(256) void gemm_epilogue(
    const bf16* __restrict__ Abf,   // [B][E]
    const bf16* __restrict__ Pbf,   // [C][E] normalized
    const int* __restrict__ targets,
    const float* __restrict__ oSimA,
    const float* __restrict__ iEffA,
    float* __restrict__ posExp,
    float* __restrict__ negExp,
    float* __restrict__ negVals,
    int* __restrict__ posCnt,
    float* __restrict__ acc4,
    int* __restrict__ ctrl,
    float* __restrict__ out) {
    __shared__ __align__(16) bf16 S[2][12 * 512];   // 12 chunks x 512 elem
    __shared__ int tgtLds[64];
    __shared__ int tkt;
    __shared__ float red[4][4];

    const int tid = threadIdx.x;
    const int wave = tid >> 6, lane = tid & 63;
    const int quad = lane >> 4, l16 = lane & 15;
    const int wRow = (wave >> 1) * 32, wCol = (wave & 1) * 64;
    const int bn0 = blockIdx.x * 128, bm0 = blockIdx.y * 64;

    if (tid < 64) tgtLds[tid] = targets[bm0 + tid];

    // staging sources: this wave's 3 chunks
    const bf16* srcs[3];
#pragma unroll
    for (int j = 0; j < 3; ++j) {
        int c = wave * 3 + j;
        srcs[j] = (c < 4)
            ? Abf + (size_t)(bm0 + c * 16 + l16) * E_SZ + quad * 8
            : Pbf + (size_t)(bn0 + (c - 4) * 16 + l16) * E_SZ + quad * 8;
    }

    int colG[4]; float oS[4], iE[4];
#pragma unroll
    for (int ni = 0; ni < 4; ++ni) {
        colG[ni] = bn0 + wCol + ni * 16 + l16;
        oS[ni] = oSimA[colG[ni]];
        iE[ni] = iEffA[colG[ni]];
    }

    f32x4 zero = {0.f, 0.f, 0.f, 0.f};
    f32x4 acc[2][4];
#pragma unroll
    for (int i = 0; i < 2; ++i)
#pragma unroll
        for (int j = 0; j < 4; ++j) acc[i][j] = zero;

#define STAGE(K0, BUF)                                                   \
    {                                                                    \
        _Pragma("unroll")                                                \
        for (int j = 0; j < 3; ++j)                                      \
            async16(srcs[j] + (K0), &S[BUF][(wave * 3 + j) * 512]);      \
    }

    STAGE(0, 0)
#pragma unroll
    for (int kk = 0; kk < 16; ++kk) {
        __syncthreads();
        if (kk < 15) STAGE((kk + 1) * 32, (kk + 1) & 1)
        const int bsel = kk & 1;
        bf16x8 af[2], bff[4];
#pragma unroll
        for (int mi = 0; mi < 2; ++mi)
            af[mi] = *(const bf16x8*)&S[bsel][((wRow >> 4) + mi) * 512 + quad * 128 + l16 * 8];
#pragma unroll
        for (int ni = 0; ni < 4; ++ni)
            bff[ni] = *(const bf16x8*)&S[bsel][2048 + ((wCol >> 4) + ni) * 512 + quad * 128 + l16 * 8];
#pragma unroll
        for (int mi = 0; mi < 2; ++mi)
#pragma unroll
            for (int ni = 0; ni < 4; ++ni)
                acc[mi][ni] = __builtin_amdgcn_mfma_f32_16x16x32_bf16(
                    af[mi], bff[ni], acc[mi][ni], 0, 0, 0);
    }
#undef STAGE

    // -------- epilogue: per-class (column) reductions --------
    float negE[4] = {0.f, 0.f, 0.f, 0.f};
    float negV[4] = {0.f, 0.f, 0.f, 0.f};
#pragma unroll
    for (int mi = 0; mi < 2; ++mi) {
#pragma unroll
        for (int r = 0; r < 4; ++r) {
            int rowL = wRow + mi * 16 + quad * 4 + r;
            int tgt = tgtLds[rowL];
#pragma unroll
            for (int ni = 0; ni < 4; ++ni) {
                float cosv = acc[mi][ni][r];
                if (tgt == colG[ni]) {
                    atomicAdd(&posExp[colG[ni]], __expf(ALPHA * (MRG - cosv)));
                    atomicAdd(&posCnt[colG[ni]], 1);
                } else {
                    float nv = (cosv < oS[ni]) ? iE[ni] : 1.0f;
                    negE[ni] += __expf(ALPHA * (cosv + MRG) * nv);
                    negV[ni] += nv;
                }
            }
        }
    }
#pragma unroll
    for (int ni = 0; ni < 4; ++ni) {
        float e = negE[ni], v = negV[ni];
        e += __shfl_xor(e, 16); e += __shfl_xor(e, 32);
        v += __shfl_xor(v, 16); v += __shfl_xor(v, 32);
        if (quad == 0) {
            atomicAdd(&negExp[colG[ni]], e);
            atomicAdd(&negVals[colG[ni]], v);
        }
    }

    // -------- ticket: last NFIN blocks do the finalize --------
    int* ticket = ctrl;
    int* flag = ctrl + 1;
    int* ticket2 = ctrl + 2;
    __threadfence();
    if (tid == 0) tkt = atomicAdd(ticket, 1);
    __syncthreads();
    int t = tkt;
    if (t < NBLK - NFIN) return;
    int fb = t - (NBLK - NFIN);     // 0..63
    if (tid == 0) {
        if (t == NBLK - 1)
            __hip_atomic_store(flag, 1, __ATOMIC_RELEASE, __HIP_MEMORY_SCOPE_AGENT);
        while (__hip_atomic_load(flag, __ATOMIC_ACQUIRE, __HIP_MEMORY_SCOPE_AGENT) == 0)
            __builtin_amdgcn_s_sleep(8);
    }
    __syncthreads();
    __threadfence();

    int c = fb * 256 + tid;
    float pe = __hip_atomic_load(&posExp[c], __ATOMIC_RELAXED, __HIP_MEMORY_SCOPE_AGENT);
    float ne = __hip_atomic_load(&negExp[c], __ATOMIC_RELAXED, __HIP_MEMORY_SCOPE_AGENT);
    float nv = __hip_atomic_load(&negVals[c], __ATOMIC_RELAXED, __HIP_MEMORY_SCOPE_AGENT);
    int cnt = __hip_atomic_load(&posCnt[c], __ATOMIC_RELAXED, __HIP_MEMORY_SCOPE_AGENT);
    float pt = log1pf(pe);
    float nt = log1pf(ne);
    float pws = (cnt > 0) ? 1.0f : 0.0f;
    int Nc = B_SZ - cnt;
    float nws = (Nc > 0) ? nv / (float)Nc : 0.0f;
#pragma unroll
    for (int m = 1; m < 64; m <<= 1) {
        pt += __shfl_xor(pt, m);
        nt += __shfl_xor(nt, m);
        pws += __shfl_xor(pws, m);
        nws += __shfl_xor(nws, m);
    }
    if ((tid & 63) == 0) {
        red[wave][0] = pt; red[wave][1] = nt; red[wave][2] = pws; red[wave][3] = nws;
    }
    __syncthreads();
    if (tid < 4) {
        float s = red[0][tid] + red[1][tid] + red[2][tid] + red[3][tid];
        atomicAdd(&acc4[tid], s);
    }
    __syncthreads();
    if (tid == 0) {
        __threadfence();
        if (atomicAdd(ticket2, 1) == NFIN - 1) {
            float a0 = atomicAdd(&acc4[0], 0.f);
            float a1 = atomicAdd(&acc4[1], 0.f);
            float a2 = atomicAdd(&acc4[2], 0.f);
            float a3 = atomicAdd(&acc4[3], 0.f);
            out[0] = a0 / a2 + a1 / a3;
        }
    }
}

extern "C" void kernel_launch(void* const* d_in, const int* in_sizes, int n_in,
                              void* d_out, int out_size, void* d_ws, size_t ws_size,
                              hipStream_t stream) {
    const float* inputs = (const float*)d_in[0];
    const int* targets = (const int*)d_in[1];
    const float* proxies = (const float*)d_in[2];
    const float* effNum = (const float*)d_in[3];
    const float* lSim = (const float*)d_in[4];
    float* out = (float*)d_out;

    // workspace layout
    bf16* Pbf = (bf16*)d_ws;                        // C*E bf16  (16 MB)
    bf16* Abf = Pbf + (size_t)C_SZ * E_SZ;          // B*E bf16  (1 MB)
    float* oSim = (float*)(Abf + (size_t)B_SZ * E_SZ);
    float* iEff = oSim + C_SZ;
    float* posExp = iEff + C_SZ;
    float* negExp = posExp + C_SZ;
    float* negVals = negExp + C_SZ;
    int* posCnt = (int*)(negVals + C_SZ);
    float* acc4 = (float*)(posCnt + C_SZ);
    int* ctrl = (int*)(acc4 + 8);                   // ticket, flag, ticket2

    prologue<<<4096 + 256, 256, 0, stream>>>(proxies, Pbf, effNum, lSim, inputs,
                                             Abf, oSim, iEff, posExp, negExp,
                                             negVals, posCnt, acc4, ctrl);
    gemm_epilogue<<<dim3(C_SZ / 128, B_SZ / 64), 256, 0, stream>>>(
        Abf, Pbf, targets, oSim, iEff, posExp, negExp, negVals, posCnt,
        acc4, ctrl, out);
}